// Round 22
// baseline (570.637 us; speedup 1.0000x reference)
//
#include <hip/hip_runtime.h>
#include <hip/hip_bf16.h>
#include <cstdint>

// ---------------- Threefry2x32 (JAX-compatible, 20 rounds) ----------------
__device__ __forceinline__ uint32_t rotl32(uint32_t v, int n) {
    return (v << n) | (v >> (32 - n));
}

__device__ __forceinline__ void threefry2x32(uint32_t k0, uint32_t k1,
                                             uint32_t x0, uint32_t x1,
                                             uint32_t& o0, uint32_t& o1) {
    uint32_t ks2 = 0x1BD11BDAu ^ k0 ^ k1;
    uint32_t v0 = x0 + k0, v1 = x1 + k1;
    v0 += v1; v1 = rotl32(v1, 13); v1 ^= v0;
    v0 += v1; v1 = rotl32(v1, 15); v1 ^= v0;
    v0 += v1; v1 = rotl32(v1, 26); v1 ^= v0;
    v0 += v1; v1 = rotl32(v1, 6);  v1 ^= v0;
    v0 += k1; v1 += ks2 + 1u;
    v0 += v1; v1 = rotl32(v1, 17); v1 ^= v0;
    v0 += v1; v1 = rotl32(v1, 29); v1 ^= v0;
    v0 += v1; v1 = rotl32(v1, 16); v1 ^= v0;
    v0 += v1; v1 = rotl32(v1, 24); v1 ^= v0;
    v0 += ks2; v1 += k0 + 2u;
    v0 += v1; v1 = rotl32(v1, 13); v1 ^= v0;
    v0 += v1; v1 = rotl32(v1, 15); v1 ^= v0;
    v0 += v1; v1 = rotl32(v1, 26); v1 ^= v0;
    v0 += v1; v1 = rotl32(v1, 6);  v1 ^= v0;
    v0 += k0; v1 += k1 + 3u;
    v0 += v1; v1 = rotl32(v1, 17); v1 ^= v0;
    v0 += v1; v1 = rotl32(v1, 29); v1 ^= v0;
    v0 += v1; v1 = rotl32(v1, 16); v1 ^= v0;
    v0 += v1; v1 = rotl32(v1, 24); v1 ^= v0;
    v0 += k1; v1 += ks2 + 4u;
    v0 += v1; v1 = rotl32(v1, 13); v1 ^= v0;
    v0 += v1; v1 = rotl32(v1, 15); v1 ^= v0;
    v0 += v1; v1 = rotl32(v1, 26); v1 ^= v0;
    v0 += v1; v1 = rotl32(v1, 6);  v1 ^= v0;
    v0 += ks2; v1 += k0 + 5u;
    o0 = v0; o1 = v1;
}

__device__ __forceinline__ float bits_to_unit_float(uint32_t bits) {
    return __uint_as_float((bits >> 9) | 0x3F800000u) - 1.0f;
}

__device__ __forceinline__ float erfinv_f(float x) {
    float w = -log1pf(-x * x);
    float p;
    if (w < 5.0f) {
        w = w - 2.5f;
        p = 2.81022636e-08f;
        p = fmaf(p, w, 3.43273939e-07f);
        p = fmaf(p, w, -3.5233877e-06f);
        p = fmaf(p, w, -4.39150654e-06f);
        p = fmaf(p, w, 0.00021858087f);
        p = fmaf(p, w, -0.00125372503f);
        p = fmaf(p, w, -0.00417768164f);
        p = fmaf(p, w, 0.246640727f);
        p = fmaf(p, w, 1.50140941f);
    } else {
        w = sqrtf(w) - 3.0f;
        p = -0.000200214257f;
        p = fmaf(p, w, 0.000100950558f);
        p = fmaf(p, w, 0.00134934322f);
        p = fmaf(p, w, -0.00367342844f);
        p = fmaf(p, w, 0.00573950773f);
        p = fmaf(p, w, -0.0076224613f);
        p = fmaf(p, w, 0.00943887047f);
        p = fmaf(p, w, 1.00167406f);
        p = fmaf(p, w, 2.83297682f);
    }
    return p * x;
}

// ---------------- weight transposes: W2 [256][576]->[576][256]; W1 [64][294]->[294][64] ----------------
__global__ __launch_bounds__(256) void transpose_W2(const float* __restrict__ W2,
                                                    float* __restrict__ W2T,
                                                    const float* __restrict__ W1,
                                                    float* __restrict__ W1T) {
    __shared__ float t[32][33];
    int pT = blockIdx.x % 18;
    int oT = blockIdx.x / 18;
    int c = threadIdx.x & 31, r8 = threadIdx.x >> 5;
    #pragma unroll
    for (int rr = 0; rr < 4; ++rr) {
        int oc = oT * 32 + r8 + 8 * rr;
        t[r8 + 8 * rr][c] = W2[oc * 576 + pT * 32 + c];
    }
    __syncthreads();
    #pragma unroll
    for (int rr = 0; rr < 4; ++rr) {
        int p = pT * 32 + r8 + 8 * rr;
        W2T[p * 256 + oT * 32 + c] = t[c][r8 + 8 * rr];
    }
    // W1 transpose folded in (tiny): 18816 elements over 144 blocks
    for (int idx = blockIdx.x * 256 + threadIdx.x; idx < 18816; idx += 144 * 256) {
        int oc = idx / 294, p = idx % 294;
        W1T[p * 64 + oc] = W1[idx];
    }
}

// ---------------- conv1 (6->64, 7x7, s4, p3) + relu ----------------
// Weights read DIRECTLY from global W1T (L2-hot, wave-uniform address -> scalar
// loads). NO LDS, NO barriers: frees the LDS pipe (was ~86% loaded) and lets
// waves slide to hide latency. FMA order identical to R12.
// block: 512 thr = 64 oc x 8 oh x 56 ow; thread: 8 oc x 7 ow.
// grid = 64 b * 7 ohT = 448
__global__ __launch_bounds__(512) void conv1_tiled(const float* __restrict__ x,
                                                   const float* __restrict__ W1T,
                                                   const float* __restrict__ b1,
                                                   float* __restrict__ out) {
    int bid = blockIdx.x;
    int ohT = bid % 7;
    int b   = bid / 7;
    int tid = threadIdx.x;
    int ocg = tid >> 6;          // 8 groups x 8 oc (uniform per wave)
    int ohh = (tid >> 3) & 7;    // 8 rows
    int owg = tid & 7;           // 8 groups x 7 ow

    int oh = ohT * 8 + ohh;
    int iwst = 28 * owg - 4;
    const float* xb = x + (size_t)b * 6 * 50176;

    float acc[8][7] = {};

    #pragma unroll 1
    for (int ic = 0; ic < 6; ++ic) {
        #pragma unroll 1
        for (int kh = 0; kh < 7; ++kh) {
            int ih = 4 * oh - 3 + kh;
            if ((unsigned)ih >= 224u) continue;   // wave-uniform
            const float* xrow = xb + ic * 50176 + ih * 224 + iwst;
            float r[32];
            {
                float2 v0 = (owg > 0) ? *reinterpret_cast<const float2*>(xrow)
                                      : make_float2(0.0f, 0.0f);
                float2 v1 = (owg > 0) ? *reinterpret_cast<const float2*>(xrow + 2)
                                      : make_float2(0.0f, 0.0f);
                r[0] = v0.x; r[1] = v0.y; r[2] = v1.x; r[3] = v1.y;
            }
            #pragma unroll
            for (int t = 2; t < 16; ++t) {
                float2 v2 = *reinterpret_cast<const float2*>(xrow + 2 * t);
                r[2 * t] = v2.x; r[2 * t + 1] = v2.y;
            }
            const float* wp = W1T + (ic * 49 + kh * 7) * 64 + 8 * ocg;
            #pragma unroll
            for (int kw = 0; kw < 7; ++kw) {
                float4 wa = *reinterpret_cast<const float4*>(wp + kw * 64);
                float4 wb = *reinterpret_cast<const float4*>(wp + kw * 64 + 4);
                #pragma unroll
                for (int j = 0; j < 7; ++j) {
                    float xv = r[4 * j + kw + 1];
                    acc[0][j] = fmaf(xv, wa.x, acc[0][j]);
                    acc[1][j] = fmaf(xv, wa.y, acc[1][j]);
                    acc[2][j] = fmaf(xv, wa.z, acc[2][j]);
                    acc[3][j] = fmaf(xv, wa.w, acc[3][j]);
                    acc[4][j] = fmaf(xv, wb.x, acc[4][j]);
                    acc[5][j] = fmaf(xv, wb.y, acc[5][j]);
                    acc[6][j] = fmaf(xv, wb.z, acc[6][j]);
                    acc[7][j] = fmaf(xv, wb.w, acc[7][j]);
                }
            }
        }
    }

    int oc0 = 8 * ocg;
    #pragma unroll
    for (int q = 0; q < 8; ++q) {
        float bias = b1[oc0 + q];
        float* orow = out + (((size_t)b * 64 + oc0 + q) * 56 + oh) * 56 + 7 * owg;
        #pragma unroll
        for (int j = 0; j < 7; ++j) orow[j] = fmaxf(acc[q][j] + bias, 0.0f);
    }
}

// ---------------- conv2 (64->256, 3x3, s2, p1) + relu + partial pool ----------------
// Weights read DIRECTLY from global W2T (2.3 MB, identical across blocks ->
// fully L2-resident; 4 distinct 16B addresses per wave per read). NO weight
// LDS, NO barriers in the K-loop. LDS only for the final 16 KB reduce.
// FMA order (ic 0..63, kh, kw, j) byte-identical to R12.
// block: 512 thr = 256 oc x 4 oh x 28 ow; thread: 8 oc (4+4 split) x 7 ow.
// grid = 64 b * 7 ohT = 448
__global__ __launch_bounds__(512) void conv2_tiled(const float* __restrict__ c1,
                                                   const float* __restrict__ W2T,
                                                   const float* __restrict__ b2,
                                                   float* __restrict__ part2) {
    int bid = blockIdx.x;
    int ohT = bid % 7;
    int b   = bid / 7;
    int tid = threadIdx.x;
    int ocg = tid >> 4;          // 0..31, 8 oc each (ocg*4.. and 128+ocg*4..)
    int ohh = (tid >> 2) & 3;    // 4 rows
    int owg = tid & 3;           // 4 groups x 7 ow = 28 ow

    __shared__ float red[256 * 16];   // 16 KB (reduce only)

    int oh = 4 * ohT + ohh;
    int start = 14 * owg - 2;    // r[rel] holds iw = start + rel; used rel in [1,15]

    float acc[8][7] = {};

    #pragma unroll 1
    for (int ic = 0; ic < 64; ++ic) {
        const float* crow0 = c1 + ((size_t)b * 64 + ic) * 3136;
        #pragma unroll 1
        for (int kh = 0; kh < 3; ++kh) {
            int ih = 2 * oh - 1 + kh;
            if ((unsigned)ih >= 56u) continue;   // divergent only at oh=0,kh=0
            const float* xrow = crow0 + ih * 56 + start;
            float r[16];
            {
                float2 v0 = (owg > 0) ? *reinterpret_cast<const float2*>(xrow)
                                      : make_float2(0.0f, 0.0f);
                r[0] = v0.x; r[1] = v0.y;
            }
            #pragma unroll
            for (int t = 1; t < 8; ++t) {
                float2 v2 = *reinterpret_cast<const float2*>(xrow + 2 * t);
                r[2 * t] = v2.x; r[2 * t + 1] = v2.y;
            }
            const float* wrow = W2T + ((size_t)(ic * 9 + kh * 3)) * 256;
            #pragma unroll
            for (int kw = 0; kw < 3; ++kw) {
                float4 wa = *reinterpret_cast<const float4*>(wrow + kw * 256 + 4 * ocg);
                float4 wb = *reinterpret_cast<const float4*>(wrow + kw * 256 + 128 + 4 * ocg);
                #pragma unroll
                for (int j = 0; j < 7; ++j) {
                    float xv = r[2 * j + kw + 1];
                    acc[0][j] = fmaf(xv, wa.x, acc[0][j]);
                    acc[1][j] = fmaf(xv, wa.y, acc[1][j]);
                    acc[2][j] = fmaf(xv, wa.z, acc[2][j]);
                    acc[3][j] = fmaf(xv, wa.w, acc[3][j]);
                    acc[4][j] = fmaf(xv, wb.x, acc[4][j]);
                    acc[5][j] = fmaf(xv, wb.y, acc[5][j]);
                    acc[6][j] = fmaf(xv, wb.z, acc[6][j]);
                    acc[7][j] = fmaf(xv, wb.w, acc[7][j]);
                }
            }
        }
    }

    // bias + relu + per-thread 7-ow partial sums; block reduce (fixed order)
    int sp = ohh * 4 + owg;      // 0..15
    #pragma unroll
    for (int q = 0; q < 8; ++q) {
        int ocl = (q < 4) ? (ocg * 4 + q) : (128 + ocg * 4 + (q - 4));
        float bias = b2[ocl];
        float s = 0.0f;
        #pragma unroll
        for (int j = 0; j < 7; ++j) s += fmaxf(acc[q][j] + bias, 0.0f);
        red[ocl * 16 + sp] = s;
    }
    __syncthreads();
    if (tid < 256) {
        float s = 0.0f;
        #pragma unroll
        for (int i = 0; i < 16; ++i) s += red[tid * 16 + i];
        part2[((size_t)ohT * 64 + b) * 256 + tid] = s;
    }
}

// ---------------- head: pool (7 slices) + fc_h + mu + kappa (fused) ----------------
// d_out layout: out[0:448], mu[448:2496], kappa[2496:2560]
__global__ __launch_bounds__(512) void head_fused(const float* __restrict__ part2,
                                                  const float* __restrict__ Wh,
                                                  const float* __restrict__ bh,
                                                  const float* __restrict__ Wmu,
                                                  const float* __restrict__ bmu,
                                                  const float* __restrict__ Wk,
                                                  const float* __restrict__ bk,
                                                  float* __restrict__ out) {
    int b = blockIdx.x, tid = threadIdx.x;
    __shared__ float ps[256], hs[512], ms[32], red2[512], kred[16];
    __shared__ float nrm;
    if (tid < 256) {
        float s = 0.0f;
        #pragma unroll
        for (int t = 0; t < 7; ++t) s += part2[((size_t)t * 64 + b) * 256 + tid];
        ps[tid] = s * (1.0f / 784.0f);
    }
    __syncthreads();
    {
        float acc = bh[tid];
        for (int i = 0; i < 256; ++i) acc = fmaf(ps[i], Wh[i * 512 + tid], acc);
        hs[tid] = acc;
    }
    __syncthreads();
    {
        int m = tid >> 4, part = tid & 15;
        int j0 = part * 32;
        float acc = 0.0f;
        #pragma unroll
        for (int jj = 0; jj < 32; ++jj) acc = fmaf(hs[j0 + jj], Wmu[(j0 + jj) * 32 + m], acc);
        red2[m * 16 + part] = acc;
    }
    if (tid < 16) {
        int j0 = tid * 32;
        float acc = 0.0f;
        #pragma unroll
        for (int jj = 0; jj < 32; ++jj) acc = fmaf(hs[j0 + jj], Wk[j0 + jj], acc);
        kred[tid] = acc;
    }
    __syncthreads();
    if (tid < 32) {
        float acc = bmu[tid];
        #pragma unroll
        for (int p = 0; p < 16; ++p) acc += red2[tid * 16 + p];
        ms[tid] = acc;
    }
    if (tid == 32) {
        float acc = bk[0];
        #pragma unroll
        for (int p = 0; p < 16; ++p) acc += kred[p];
        float sp = fmaxf(acc, 0.0f) + log1pf(expf(-fabsf(acc)));
        out[2496 + b] = sp + 1.0f;
    }
    __syncthreads();
    if (tid == 0) {
        float ss = 0.0f;
        for (int k = 0; k < 32; ++k) ss += ms[k] * ms[k];
        nrm = sqrtf(fmaxf(ss, 1e-24f));
    }
    __syncthreads();
    if (tid < 32) out[448 + b * 32 + tid] = ms[tid] / nrm;
}

// ---------------- MLP head with fused vMF sampling ----------------
__global__ __launch_bounds__(512) void mlp_head(const float* __restrict__ M1, const float* __restrict__ bM1,
                                                const float* __restrict__ M2, const float* __restrict__ bM2,
                                                const float* __restrict__ M3, const float* __restrict__ bM3,
                                                const float* __restrict__ M4, const float* __restrict__ bM4,
                                                float* __restrict__ out) {
    int b = blockIdx.x;
    int tid = threadIdx.x;
    __shared__ float vsh[31], wcs[10], zsh[32], y1[512], y2[512], y3[32];
    __shared__ int accs[10];

    // ---- vMF phase ----
    if (tid < 31) {
        uint32_t y00, y01, y10, y11;
        threefry2x32(0u, 42u, 0u, 2u, y00, y01);
        threefry2x32(0u, 42u, 1u, 3u, y10, y11);
        uint32_t kv0 = y01, kv1 = y11;
        int idx = b * 31 + tid;
        int word = (idx >= 992);
        uint32_t pp = (uint32_t)(word ? idx - 992 : idx);
        uint32_t a0, a1;
        threefry2x32(kv0, kv1, pp, 992u + pp, a0, a1);
        uint32_t bits = word ? a1 : a0;
        float f = bits_to_unit_float(bits);
        const float LO = -0.99999994f;
        float u = fmaxf(LO, f * 2.0f + LO);
        vsh[tid] = 1.41421356f * erfinv_f(u);
    } else if (tid >= 64 && tid < 74) {
        uint32_t y00, y01, y10, y11;
        threefry2x32(0u, 42u, 0u, 2u, y00, y01);
        threefry2x32(0u, 42u, 1u, 3u, y10, y11);
        uint32_t kw0 = y00, kw1 = y10;
        int i = tid - 64;
        float kappa = out[2496 + b];
        uint32_t k10, k11, k20, k21, z0, z1;
        threefry2x32(kw0, kw1, 0u, (uint32_t)(2 * i), k10, k11);
        threefry2x32(kw0, kw1, 0u, (uint32_t)(2 * i + 1), k20, k21);
        uint32_t p = (uint32_t)(b & 31);
        threefry2x32(k10, k11, p, 32u + p, z0, z1);
        uint32_t bits = (b < 32) ? z0 : z1;
        float u1 = bits_to_unit_float(bits);
        float wc = 2.0f * u1 - 1.0f;
        float om = fmaxf(1.0f - wc * wc, 1e-40f);
        float logp = kappa * wc + 14.5f * logf(om);
        threefry2x32(k20, k21, p, 32u + p, z0, z1);
        bits = (b < 32) ? z0 : z1;
        float logr = logf(bits_to_unit_float(bits) + 1e-40f);
        wcs[i] = wc;
        accs[i] = (logr + kappa <= logp) ? 1 : 0;
    }
    __syncthreads();
    if (tid == 0) {
        float w = 0.0f;
        bool acc = false;
        #pragma unroll
        for (int i = 0; i < 10; ++i) {
            bool newly = (accs[i] != 0) && !acc;
            if (newly) w = wcs[i];
            acc = acc || newly;
        }
        w = fminf(fmaxf(w, -1.0f), 1.0f);
        float ss = 0.0f;
        #pragma unroll
        for (int j = 0; j < 31; ++j) ss += vsh[j] * vsh[j];
        float vinv = 1.0f / sqrtf(fmaxf(ss, 1e-24f));
        float st = sqrtf(fmaxf(1.0f - w * w, 1e-40f));
        float zt[32];
        #pragma unroll
        for (int j = 0; j < 31; ++j) zt[j] = st * (vsh[j] * vinv);
        zt[31] = w;
        float uv[32];
        float us = 0.0f;
        #pragma unroll
        for (int k = 0; k < 32; ++k) {
            float m = out[448 + b * 32 + k];
            float e = (k == 31) ? 1.0f : 0.0f;
            float t = e - m;
            uv[k] = t;
            us += t * t;
        }
        float un = sqrtf(fmaxf(us, 1e-24f));
        float dot = 0.0f;
        #pragma unroll
        for (int k = 0; k < 32; ++k) {
            uv[k] = uv[k] / un;
            dot += zt[k] * uv[k];
        }
        #pragma unroll
        for (int k = 0; k < 32; ++k) zsh[k] = zt[k] - 2.0f * dot * uv[k];
    }
    __syncthreads();

    // ---- MLP ----
    float acc = bM1[tid];
    #pragma unroll
    for (int k = 0; k < 32; k++) acc = fmaf(zsh[k], M1[k * 512 + tid], acc);
    y1[tid] = fmaxf(acc, 0.0f);
    __syncthreads();
    acc = bM2[tid];
    for (int k = 0; k < 512; k++) acc = fmaf(y1[k], M2[k * 512 + tid], acc);
    y2[tid] = fmaxf(acc, 0.0f);
    __syncthreads();
    if (tid < 32) {
        acc = bM3[tid];
        for (int k = 0; k < 512; k++) acc = fmaf(y2[k], M3[k * 32 + tid], acc);
        y3[tid] = fmaxf(acc, 0.0f);
    }
    __syncthreads();
    if (tid < 7) {
        acc = bM4[tid];
        #pragma unroll
        for (int k = 0; k < 32; k++) acc = fmaf(y3[k], M4[k * 7 + tid], acc);
        out[b * 7 + tid] = acc;
    }
}

extern "C" void kernel_launch(void* const* d_in, const int* in_sizes, int n_in,
                              void* d_out, int out_size, void* d_ws, size_t ws_size,
                              hipStream_t stream) {
    const float* x   = (const float*)d_in[0];
    const float* W1  = (const float*)d_in[1];
    const float* b1  = (const float*)d_in[2];
    const float* W2  = (const float*)d_in[3];
    const float* b2  = (const float*)d_in[4];
    const float* Wh  = (const float*)d_in[5];
    const float* bh  = (const float*)d_in[6];
    const float* Wmu = (const float*)d_in[7];
    const float* bmu = (const float*)d_in[8];
    const float* Wk  = (const float*)d_in[9];
    const float* bk  = (const float*)d_in[10];
    const float* M1  = (const float*)d_in[11];
    const float* bM1 = (const float*)d_in[12];
    const float* M2  = (const float*)d_in[13];
    const float* bM2 = (const float*)d_in[14];
    const float* M3  = (const float*)d_in[15];
    const float* bM3 = (const float*)d_in[16];
    const float* M4  = (const float*)d_in[17];
    const float* bM4 = (const float*)d_in[18];

    float* out = (float*)d_out;
    float* ws  = (float*)d_ws;

    // workspace layout (floats)
    float* W2T     = ws;                   // 147456
    float* W1T     = W2T + 147456;         // 18816
    float* c1      = W1T + 18816;          // 12845056
    float* pooledp = c1 + 12845056;        // 7*64*256 = 114688

    transpose_W2<<<144, 256, 0, stream>>>(W2, W2T, W1, W1T);
    conv1_tiled<<<448, 512, 0, stream>>>(x, W1T, b1, c1);
    conv2_tiled<<<448, 512, 0, stream>>>(c1, W2T, b2, pooledp);
    head_fused<<<64, 512, 0, stream>>>(pooledp, Wh, bh, Wmu, bmu, Wk, bk, out);
    mlp_head<<<64, 512, 0, stream>>>(M1, bM1, M2, bM2, M3, bM3, M4, bM4, out);
}

// Round 23
// 387.058 us; speedup vs baseline: 1.4743x; 1.4743x over previous
//
#include <hip/hip_runtime.h>
#include <hip/hip_bf16.h>
#include <cstdint>

// ---------------- Threefry2x32 (JAX-compatible, 20 rounds) ----------------
__device__ __forceinline__ uint32_t rotl32(uint32_t v, int n) {
    return (v << n) | (v >> (32 - n));
}

__device__ __forceinline__ void threefry2x32(uint32_t k0, uint32_t k1,
                                             uint32_t x0, uint32_t x1,
                                             uint32_t& o0, uint32_t& o1) {
    uint32_t ks2 = 0x1BD11BDAu ^ k0 ^ k1;
    uint32_t v0 = x0 + k0, v1 = x1 + k1;
    v0 += v1; v1 = rotl32(v1, 13); v1 ^= v0;
    v0 += v1; v1 = rotl32(v1, 15); v1 ^= v0;
    v0 += v1; v1 = rotl32(v1, 26); v1 ^= v0;
    v0 += v1; v1 = rotl32(v1, 6);  v1 ^= v0;
    v0 += k1; v1 += ks2 + 1u;
    v0 += v1; v1 = rotl32(v1, 17); v1 ^= v0;
    v0 += v1; v1 = rotl32(v1, 29); v1 ^= v0;
    v0 += v1; v1 = rotl32(v1, 16); v1 ^= v0;
    v0 += v1; v1 = rotl32(v1, 24); v1 ^= v0;
    v0 += ks2; v1 += k0 + 2u;
    v0 += v1; v1 = rotl32(v1, 13); v1 ^= v0;
    v0 += v1; v1 = rotl32(v1, 15); v1 ^= v0;
    v0 += v1; v1 = rotl32(v1, 26); v1 ^= v0;
    v0 += v1; v1 = rotl32(v1, 6);  v1 ^= v0;
    v0 += k0; v1 += k1 + 3u;
    v0 += v1; v1 = rotl32(v1, 17); v1 ^= v0;
    v0 += v1; v1 = rotl32(v1, 29); v1 ^= v0;
    v0 += v1; v1 = rotl32(v1, 16); v1 ^= v0;
    v0 += v1; v1 = rotl32(v1, 24); v1 ^= v0;
    v0 += k1; v1 += ks2 + 4u;
    v0 += v1; v1 = rotl32(v1, 13); v1 ^= v0;
    v0 += v1; v1 = rotl32(v1, 15); v1 ^= v0;
    v0 += v1; v1 = rotl32(v1, 26); v1 ^= v0;
    v0 += v1; v1 = rotl32(v1, 6);  v1 ^= v0;
    v0 += ks2; v1 += k0 + 5u;
    o0 = v0; o1 = v1;
}

__device__ __forceinline__ float bits_to_unit_float(uint32_t bits) {
    return __uint_as_float((bits >> 9) | 0x3F800000u) - 1.0f;
}

__device__ __forceinline__ float erfinv_f(float x) {
    float w = -log1pf(-x * x);
    float p;
    if (w < 5.0f) {
        w = w - 2.5f;
        p = 2.81022636e-08f;
        p = fmaf(p, w, 3.43273939e-07f);
        p = fmaf(p, w, -3.5233877e-06f);
        p = fmaf(p, w, -4.39150654e-06f);
        p = fmaf(p, w, 0.00021858087f);
        p = fmaf(p, w, -0.00125372503f);
        p = fmaf(p, w, -0.00417768164f);
        p = fmaf(p, w, 0.246640727f);
        p = fmaf(p, w, 1.50140941f);
    } else {
        w = sqrtf(w) - 3.0f;
        p = -0.000200214257f;
        p = fmaf(p, w, 0.000100950558f);
        p = fmaf(p, w, 0.00134934322f);
        p = fmaf(p, w, -0.00367342844f);
        p = fmaf(p, w, 0.00573950773f);
        p = fmaf(p, w, -0.0076224613f);
        p = fmaf(p, w, 0.00943887047f);
        p = fmaf(p, w, 1.00167406f);
        p = fmaf(p, w, 2.83297682f);
    }
    return p * x;
}

// ---------------- W2 transpose: [256][576] -> [576][256] ----------------
__global__ __launch_bounds__(256) void transpose_W2(const float* __restrict__ W2,
                                                    float* __restrict__ W2T) {
    __shared__ float t[32][33];
    int pT = blockIdx.x % 18;
    int oT = blockIdx.x / 18;
    int c = threadIdx.x & 31, r8 = threadIdx.x >> 5;
    #pragma unroll
    for (int rr = 0; rr < 4; ++rr) {
        int oc = oT * 32 + r8 + 8 * rr;
        t[r8 + 8 * rr][c] = W2[oc * 576 + pT * 32 + c];
    }
    __syncthreads();
    #pragma unroll
    for (int rr = 0; rr < 4; ++rr) {
        int p = pT * 32 + r8 + 8 * rr;
        W2T[p * 256 + oT * 32 + c] = t[c][r8 + 8 * rr];
    }
}

// ---------------- conv1 (6->64, 7x7, s4, p3) + relu (R12 form — best known) --------
// block: 512 thr = 64 oc x 8 oh x 56 ow; thread: 8 oc x 7 ow. grid = 448
__global__ __launch_bounds__(512) void conv1_tiled(const float* __restrict__ x,
                                                   const float* __restrict__ W1,
                                                   const float* __restrict__ b1,
                                                   float* __restrict__ out) {
    int bid = blockIdx.x;
    int ohT = bid % 7;
    int b   = bid / 7;
    int tid = threadIdx.x;
    int ocg = tid >> 6;          // 8 groups x 8 oc (uniform per wave)
    int ohh = (tid >> 3) & 7;    // 8 rows
    int owg = tid & 7;           // 8 groups x 7 ow

    __shared__ __align__(16) float w1s[294 * 64];   // 75.3 KB  [p][64]
    for (int idx = tid; idx < 18816; idx += 512) {
        int p = idx >> 6, ocl = idx & 63;
        w1s[idx] = W1[ocl * 294 + p];
    }
    __syncthreads();

    int oh = ohT * 8 + ohh;
    int iwst = 28 * owg - 4;
    const float* xb = x + (size_t)b * 6 * 50176;

    float acc[8][7] = {};

    #pragma unroll 1
    for (int ic = 0; ic < 6; ++ic) {
        #pragma unroll 1
        for (int kh = 0; kh < 7; ++kh) {
            int ih = 4 * oh - 3 + kh;
            if ((unsigned)ih >= 224u) continue;
            const float* xrow = xb + ic * 50176 + ih * 224 + iwst;
            float r[32];
            {
                float2 v0 = (owg > 0) ? *reinterpret_cast<const float2*>(xrow)
                                      : make_float2(0.0f, 0.0f);
                float2 v1 = (owg > 0) ? *reinterpret_cast<const float2*>(xrow + 2)
                                      : make_float2(0.0f, 0.0f);
                r[0] = v0.x; r[1] = v0.y; r[2] = v1.x; r[3] = v1.y;
            }
            #pragma unroll
            for (int t = 2; t < 16; ++t) {
                float2 v2 = *reinterpret_cast<const float2*>(xrow + 2 * t);
                r[2 * t] = v2.x; r[2 * t + 1] = v2.y;
            }
            const float* wp = &w1s[(ic * 49 + kh * 7) * 64 + 8 * ocg];
            #pragma unroll
            for (int kw = 0; kw < 7; ++kw) {
                float4 wa = *reinterpret_cast<const float4*>(wp + kw * 64);
                float4 wb = *reinterpret_cast<const float4*>(wp + kw * 64 + 4);
                #pragma unroll
                for (int j = 0; j < 7; ++j) {
                    float xv = r[4 * j + kw + 1];
                    acc[0][j] = fmaf(xv, wa.x, acc[0][j]);
                    acc[1][j] = fmaf(xv, wa.y, acc[1][j]);
                    acc[2][j] = fmaf(xv, wa.z, acc[2][j]);
                    acc[3][j] = fmaf(xv, wa.w, acc[3][j]);
                    acc[4][j] = fmaf(xv, wb.x, acc[4][j]);
                    acc[5][j] = fmaf(xv, wb.y, acc[5][j]);
                    acc[6][j] = fmaf(xv, wb.z, acc[6][j]);
                    acc[7][j] = fmaf(xv, wb.w, acc[7][j]);
                }
            }
        }
    }

    int oc0 = 8 * ocg;
    #pragma unroll
    for (int q = 0; q < 8; ++q) {
        float bias = b1[oc0 + q];
        float* orow = out + (((size_t)b * 64 + oc0 + q) * 56 + oh) * 56 + 7 * owg;
        #pragma unroll
        for (int j = 0; j < 7; ++j) orow[j] = fmaxf(acc[q][j] + bias, 0.0f);
    }
}

// ---------------- conv2 (64->256, 3x3, s2, p1) + relu + partial pool (R12) --------
// block: 512 thr = 256 oc x 4 oh x 28 ow; thread: 8 oc (4+4 split) x 7 ow.
// grid = 64 b * 7 ohT = 448. Balanced local optimum: FMA ~66%, LDS ~86%.
__global__ __launch_bounds__(512) void conv2_tiled(const float* __restrict__ c1,
                                                   const float* __restrict__ W2T,
                                                   const float* __restrict__ b2,
                                                   float* __restrict__ part2) {
    int bid = blockIdx.x;
    int ohT = bid % 7;
    int b   = bid / 7;
    int tid = threadIdx.x;
    int ocg = tid >> 4;          // 0..31, 8 oc each (ocg*4.. and 128+ocg*4..)
    int ohh = (tid >> 2) & 3;    // 4 rows
    int owg = tid & 3;           // 4 groups x 7 ow = 28 ow

    __shared__ __align__(16) float w2s[72 * 256];   // 73.7 KB; red overlays after compute
    float* red = w2s;            // 256 * 16 = 4096 floats

    int oh = 4 * ohT + ohh;
    int start = 14 * owg - 2;    // r[rel] holds iw = start + rel; used rel in [1,15]

    float acc[8][7] = {};

    #pragma unroll 1
    for (int chunk = 0; chunk < 8; ++chunk) {
        int ic0 = chunk * 8;
        __syncthreads();
        for (int idx4 = tid; idx4 < 4608; idx4 += 512) {
            int pl = idx4 >> 6, o4 = idx4 & 63;
            *reinterpret_cast<float4*>(&w2s[pl * 256 + o4 * 4]) =
                *reinterpret_cast<const float4*>(&W2T[((size_t)(ic0 * 9 + pl)) * 256 + o4 * 4]);
        }
        __syncthreads();

        #pragma unroll 1
        for (int icl = 0; icl < 8; ++icl) {
            const float* crow0 = c1 + ((size_t)b * 64 + ic0 + icl) * 3136;
            #pragma unroll 1
            for (int kh = 0; kh < 3; ++kh) {
                int ih = 2 * oh - 1 + kh;
                if ((unsigned)ih >= 56u) continue;
                const float* xrow = crow0 + ih * 56 + start;
                float r[16];
                {
                    float2 v0 = (owg > 0) ? *reinterpret_cast<const float2*>(xrow)
                                          : make_float2(0.0f, 0.0f);
                    r[0] = v0.x; r[1] = v0.y;
                }
                #pragma unroll
                for (int t = 1; t < 8; ++t) {
                    float2 v2 = *reinterpret_cast<const float2*>(xrow + 2 * t);
                    r[2 * t] = v2.x; r[2 * t + 1] = v2.y;
                }
                int pb = icl * 9 + kh * 3;
                #pragma unroll
                for (int kw = 0; kw < 3; ++kw) {
                    float4 wa = *reinterpret_cast<const float4*>(&w2s[(pb + kw) * 256 + 4 * ocg]);
                    float4 wb = *reinterpret_cast<const float4*>(&w2s[(pb + kw) * 256 + 128 + 4 * ocg]);
                    #pragma unroll
                    for (int j = 0; j < 7; ++j) {
                        float xv = r[2 * j + kw + 1];
                        acc[0][j] = fmaf(xv, wa.x, acc[0][j]);
                        acc[1][j] = fmaf(xv, wa.y, acc[1][j]);
                        acc[2][j] = fmaf(xv, wa.z, acc[2][j]);
                        acc[3][j] = fmaf(xv, wa.w, acc[3][j]);
                        acc[4][j] = fmaf(xv, wb.x, acc[4][j]);
                        acc[5][j] = fmaf(xv, wb.y, acc[5][j]);
                        acc[6][j] = fmaf(xv, wb.z, acc[6][j]);
                        acc[7][j] = fmaf(xv, wb.w, acc[7][j]);
                    }
                }
            }
        }
    }

    // bias + relu + per-thread 7-ow partial sums; block reduce (fixed order)
    __syncthreads();
    int sp = ohh * 4 + owg;      // 0..15
    #pragma unroll
    for (int q = 0; q < 8; ++q) {
        int ocl = (q < 4) ? (ocg * 4 + q) : (128 + ocg * 4 + (q - 4));
        float bias = b2[ocl];
        float s = 0.0f;
        #pragma unroll
        for (int j = 0; j < 7; ++j) s += fmaxf(acc[q][j] + bias, 0.0f);
        red[ocl * 16 + sp] = s;
    }
    __syncthreads();
    if (tid < 256) {
        float s = 0.0f;
        #pragma unroll
        for (int i = 0; i < 16; ++i) s += red[tid * 16 + i];
        part2[((size_t)ohT * 64 + b) * 256 + tid] = s;
    }
}

// ---------------- fused tail: pool + fc_h + mu/kappa + vMF sample + MLP ----------------
// One block per batch element b. All math bit-identical to the previous
// head_fused + mlp_head pair; mu/kappa passed via shared memory instead of
// a d_out round-trip (saves one launch + global traffic).
// d_out layout: out[0:448], mu[448:2496], kappa[2496:2560]
__global__ __launch_bounds__(512) void tail_fused(const float* __restrict__ part2,
                                                  const float* __restrict__ Wh,
                                                  const float* __restrict__ bh,
                                                  const float* __restrict__ Wmu,
                                                  const float* __restrict__ bmu,
                                                  const float* __restrict__ Wk,
                                                  const float* __restrict__ bk,
                                                  const float* __restrict__ M1, const float* __restrict__ bM1,
                                                  const float* __restrict__ M2, const float* __restrict__ bM2,
                                                  const float* __restrict__ M3, const float* __restrict__ bM3,
                                                  const float* __restrict__ M4, const float* __restrict__ bM4,
                                                  float* __restrict__ out) {
    int b = blockIdx.x, tid = threadIdx.x;
    __shared__ float ps[256], hs[512], ms[32], red2[512], kred[16];
    __shared__ float nrm, kap_sh;
    __shared__ float vsh[31], wcs[10], zsh[32], y1[512], y2[512], y3[32];
    __shared__ int accs[10];

    // ---- pool (7 slices) ----
    if (tid < 256) {
        float s = 0.0f;
        #pragma unroll
        for (int t = 0; t < 7; ++t) s += part2[((size_t)t * 64 + b) * 256 + tid];
        ps[tid] = s * (1.0f / 784.0f);
    }
    __syncthreads();
    // ---- h = ps @ Wh + bh ----
    {
        float acc = bh[tid];
        for (int i = 0; i < 256; ++i) acc = fmaf(ps[i], Wh[i * 512 + tid], acc);
        hs[tid] = acc;
    }
    __syncthreads();
    // ---- mu/kappa partials ----
    {
        int m = tid >> 4, part = tid & 15;
        int j0 = part * 32;
        float acc = 0.0f;
        #pragma unroll
        for (int jj = 0; jj < 32; ++jj) acc = fmaf(hs[j0 + jj], Wmu[(j0 + jj) * 32 + m], acc);
        red2[m * 16 + part] = acc;
    }
    if (tid < 16) {
        int j0 = tid * 32;
        float acc = 0.0f;
        #pragma unroll
        for (int jj = 0; jj < 32; ++jj) acc = fmaf(hs[j0 + jj], Wk[j0 + jj], acc);
        kred[tid] = acc;
    }
    __syncthreads();
    if (tid < 32) {
        float acc = bmu[tid];
        #pragma unroll
        for (int p = 0; p < 16; ++p) acc += red2[tid * 16 + p];
        ms[tid] = acc;
    }
    if (tid == 32) {
        float acc = bk[0];
        #pragma unroll
        for (int p = 0; p < 16; ++p) acc += kred[p];
        float sp = fmaxf(acc, 0.0f) + log1pf(expf(-fabsf(acc)));
        kap_sh = sp + 1.0f;
        out[2496 + b] = sp + 1.0f;
    }
    __syncthreads();
    if (tid == 0) {
        float ss = 0.0f;
        for (int k = 0; k < 32; ++k) ss += ms[k] * ms[k];
        nrm = sqrtf(fmaxf(ss, 1e-24f));
    }
    __syncthreads();
    if (tid < 32) out[448 + b * 32 + tid] = ms[tid] / nrm;

    // ---- vMF sampling phase (threefry bit-exact; kappa from kap_sh) ----
    if (tid < 31) {
        uint32_t y00, y01, y10, y11;
        threefry2x32(0u, 42u, 0u, 2u, y00, y01);
        threefry2x32(0u, 42u, 1u, 3u, y10, y11);
        uint32_t kv0 = y01, kv1 = y11;
        int idx = b * 31 + tid;
        int word = (idx >= 992);
        uint32_t pp = (uint32_t)(word ? idx - 992 : idx);
        uint32_t a0, a1;
        threefry2x32(kv0, kv1, pp, 992u + pp, a0, a1);
        uint32_t bits = word ? a1 : a0;
        float f = bits_to_unit_float(bits);
        const float LO = -0.99999994f;
        float u = fmaxf(LO, f * 2.0f + LO);
        vsh[tid] = 1.41421356f * erfinv_f(u);
    } else if (tid >= 64 && tid < 74) {
        uint32_t y00, y01, y10, y11;
        threefry2x32(0u, 42u, 0u, 2u, y00, y01);
        threefry2x32(0u, 42u, 1u, 3u, y10, y11);
        uint32_t kw0 = y00, kw1 = y10;
        int i = tid - 64;
        float kappa = kap_sh;
        uint32_t k10, k11, k20, k21, z0, z1;
        threefry2x32(kw0, kw1, 0u, (uint32_t)(2 * i), k10, k11);
        threefry2x32(kw0, kw1, 0u, (uint32_t)(2 * i + 1), k20, k21);
        uint32_t p = (uint32_t)(b & 31);
        threefry2x32(k10, k11, p, 32u + p, z0, z1);
        uint32_t bits = (b < 32) ? z0 : z1;
        float u1 = bits_to_unit_float(bits);
        float wc = 2.0f * u1 - 1.0f;
        float om = fmaxf(1.0f - wc * wc, 1e-40f);
        float logp = kappa * wc + 14.5f * logf(om);
        threefry2x32(k20, k21, p, 32u + p, z0, z1);
        bits = (b < 32) ? z0 : z1;
        float logr = logf(bits_to_unit_float(bits) + 1e-40f);
        wcs[i] = wc;
        accs[i] = (logr + kappa <= logp) ? 1 : 0;
    }
    __syncthreads();
    if (tid == 0) {
        float w = 0.0f;
        bool acc = false;
        #pragma unroll
        for (int i = 0; i < 10; ++i) {
            bool newly = (accs[i] != 0) && !acc;
            if (newly) w = wcs[i];
            acc = acc || newly;
        }
        w = fminf(fmaxf(w, -1.0f), 1.0f);
        float ss = 0.0f;
        #pragma unroll
        for (int j = 0; j < 31; ++j) ss += vsh[j] * vsh[j];
        float vinv = 1.0f / sqrtf(fmaxf(ss, 1e-24f));
        float st = sqrtf(fmaxf(1.0f - w * w, 1e-40f));
        float zt[32];
        #pragma unroll
        for (int j = 0; j < 31; ++j) zt[j] = st * (vsh[j] * vinv);
        zt[31] = w;
        float uv[32];
        float us = 0.0f;
        #pragma unroll
        for (int k = 0; k < 32; ++k) {
            float m = ms[k] / nrm;               // identical value to out[448+b*32+k]
            float e = (k == 31) ? 1.0f : 0.0f;
            float t = e - m;
            uv[k] = t;
            us += t * t;
        }
        float un = sqrtf(fmaxf(us, 1e-24f));
        float dot = 0.0f;
        #pragma unroll
        for (int k = 0; k < 32; ++k) {
            uv[k] = uv[k] / un;
            dot += zt[k] * uv[k];
        }
        #pragma unroll
        for (int k = 0; k < 32; ++k) zsh[k] = zt[k] - 2.0f * dot * uv[k];
    }
    __syncthreads();

    // ---- MLP 32->512->512->32->7 ----
    float acc = bM1[tid];
    #pragma unroll
    for (int k = 0; k < 32; k++) acc = fmaf(zsh[k], M1[k * 512 + tid], acc);
    y1[tid] = fmaxf(acc, 0.0f);
    __syncthreads();
    acc = bM2[tid];
    for (int k = 0; k < 512; k++) acc = fmaf(y1[k], M2[k * 512 + tid], acc);
    y2[tid] = fmaxf(acc, 0.0f);
    __syncthreads();
    if (tid < 32) {
        acc = bM3[tid];
        for (int k = 0; k < 512; k++) acc = fmaf(y2[k], M3[k * 32 + tid], acc);
        y3[tid] = fmaxf(acc, 0.0f);
    }
    __syncthreads();
    if (tid < 7) {
        acc = bM4[tid];
        #pragma unroll
        for (int k = 0; k < 32; k++) acc = fmaf(y3[k], M4[k * 7 + tid], acc);
        out[b * 7 + tid] = acc;
    }
}

extern "C" void kernel_launch(void* const* d_in, const int* in_sizes, int n_in,
                              void* d_out, int out_size, void* d_ws, size_t ws_size,
                              hipStream_t stream) {
    const float* x   = (const float*)d_in[0];
    const float* W1  = (const float*)d_in[1];
    const float* b1  = (const float*)d_in[2];
    const float* W2  = (const float*)d_in[3];
    const float* b2  = (const float*)d_in[4];
    const float* Wh  = (const float*)d_in[5];
    const float* bh  = (const float*)d_in[6];
    const float* Wmu = (const float*)d_in[7];
    const float* bmu = (const float*)d_in[8];
    const float* Wk  = (const float*)d_in[9];
    const float* bk  = (const float*)d_in[10];
    const float* M1  = (const float*)d_in[11];
    const float* bM1 = (const float*)d_in[12];
    const float* M2  = (const float*)d_in[13];
    const float* bM2 = (const float*)d_in[14];
    const float* M3  = (const float*)d_in[15];
    const float* bM3 = (const float*)d_in[16];
    const float* M4  = (const float*)d_in[17];
    const float* bM4 = (const float*)d_in[18];

    float* out = (float*)d_out;
    float* ws  = (float*)d_ws;

    // workspace layout (floats)
    float* W2T     = ws;                   // 147456
    float* c1      = W2T + 147456;         // 12845056
    float* pooledp = c1 + 12845056;        // 7*64*256 = 114688

    transpose_W2<<<144, 256, 0, stream>>>(W2, W2T);
    conv1_tiled<<<448, 512, 0, stream>>>(x, W1, b1, c1);
    conv2_tiled<<<448, 512, 0, stream>>>(c1, W2T, b2, pooledp);
    tail_fused<<<64, 512, 0, stream>>>(pooledp, Wh, bh, Wmu, bmu, Wk, bk,
                                       M1, bM1, M2, bM2, M3, bM3, M4, bM4, out);
}